// Round 8
// baseline (826.878 us; speedup 1.0000x reference)
//
#include <hip/hip_runtime.h>
#include <math.h>

#define NB 4096
#define NR 49
#define NS 50
#define ND 512
#define NK 100
#define NT 7            // score-col tiles of 16 (112 >= 100)
#define KSTEPS 16       // 512 / 32
#define NBATCH 16       // batches per block
#define NGRP (NB / NBATCH)             // 256
#define BTHREADS 448                   // 7 waves: wave w owns score-tile w
#define FRAGS (NT * KSTEPS * 64 * 8)   // 57344 ushorts (114688 B) per weight matrix

typedef __attribute__((ext_vector_type(8))) short short8;
typedef __attribute__((ext_vector_type(4))) float f32x4;

__device__ __forceinline__ unsigned short f32_bf16(float f) {
    union { float f; unsigned u; } x; x.f = f;
    return (unsigned short)((x.u + 0x7fffu + ((x.u >> 16) & 1u)) >> 16);  // RNE
}
__device__ __forceinline__ unsigned cvt_pk_bf16(float lo, float hi) {
    unsigned r;
    asm("v_cvt_pk_bf16_f32 %0, %1, %2" : "=v"(r) : "v"(lo), "v"(hi));
    return r;
}
__device__ __forceinline__ float fast_tanh(float x) {
    const float ax = fabsf(x);
    const float e = __expf(2.f * ax);            // inf for large ax -> r = 1
    const float r = 1.f - 2.f / (e + 1.f);
    return copysignf(r, x);
}

// ---------------------------------------------------------------------------
// Pre-pass: 2 weight matrices [512][100] f32 -> bf16 fragments.
// frag(t, gk): lane l holds W[k = gk*32 + (l>>4)*8 + j][col = t*16 + (l&15)].
// Used as the MFMA *A* operand (A[m = l&15][k] = W^T-tile) — layout identical
// to the B-fragment form, enabling the operand-role swap.
// ---------------------------------------------------------------------------
__global__ void preswz_kernel(const float* __restrict__ w0, const float* __restrict__ w1,
                              unsigned short* __restrict__ ws)
{
    const int l  = threadIdx.x;          // 64
    const int gk = blockIdx.x & 15;
    const int t  = blockIdx.x >> 4;      // 0..6
    const int m  = blockIdx.y;           // 0..1
    const float* W = m ? w1 : w0;
    const int col = t * 16 + (l & 15);
    const int k0  = gk * 32 + (l >> 4) * 8;
    unsigned short* o = ws + (size_t)m * FRAGS + ((size_t)(t * 16 + gk) * 64 + l) * 8;
#pragma unroll
    for (int j = 0; j < 8; ++j) {
        float v = (col < NK) ? W[(size_t)(k0 + j) * NK + col] : 0.f;
        o[j] = f32_bf16(v);
    }
}

// ---------------------------------------------------------------------------
// Main kernel: one block per (16-batch group, pass). 7 waves; wave w holds
// weight tile w (16 k-steps) in registers for the whole block lifetime.
// Per batch: 4 x {issue stage loads -> GEMM chunk -> write stage} (dbuf LDS),
// epilogue -> softmax -> weighted sum -> atomicAdd (out pre-zeroed; 2
// commutative f32 adds = deterministic).
// ---------------------------------------------------------------------------
struct SM {
    short buf[2][64 * 128];   // 2 x 16 KB bf16 feature chunks; rows 48..63 zero
    float part[NT][64];       // per-wave score partials
    float P[64];
};

__global__ __launch_bounds__(BTHREADS, 4) void coattn_main(
    const float* __restrict__ ifeat, const float* __restrict__ tfeat,
    const float* __restrict__ wPi0, const float* __restrict__ bPi0,
    const float* __restrict__ wPi1, const float* __restrict__ bPi1,
    const unsigned short* __restrict__ wsW, float* __restrict__ out)
{
    __shared__ SM sm;
    const int pass = blockIdx.x & 1;
    const int grp  = blockIdx.x >> 1;
    const int tid  = threadIdx.x;
    const int lane = tid & 63, wid = tid >> 6;   // wid 0..6 = score tile
    const int colg = lane & 15, g = lane >> 4;

    const int nrows  = pass ? NS : NR;
    const int nitems = nrows * 32;               // float4 units per 128-col chunk
    const float* featB = (pass ? tfeat : ifeat) + (size_t)grp * NBATCH * nrows * ND;
    const float* wPiRow = pass ? (wPi1 + NK) : wPi0;
    const float* bvec   = pass ? bPi1 : bPi0;

    // ---- weight tile -> registers (64 VGPRs), once per block
    short8 wreg[KSTEPS];
    {
        const unsigned short* wl = wsW + (size_t)pass * FRAGS
                                 + ((size_t)wid * KSTEPS * 64 + lane) * 8;
#pragma unroll
        for (int ks = 0; ks < KSTEPS; ++ks)
            wreg[ks] = *reinterpret_cast<const short8*>(wl + ks * 512);
    }

    // ---- zero rows [48,64) of both buffers (r-tile 3 reads them as zeros)
    for (int u = tid; u < 512; u += BTHREADS) {
        const int bsel = u >> 8, uu = u & 255;
        const int r = 48 + (uu >> 4), q = uu & 15;
        *reinterpret_cast<uint4*>(&sm.buf[bsel][r * 128 + q * 8]) = uint4{0u, 0u, 0u, 0u};
    }
    __syncthreads();

    // ---- prologue: stage chunk 0 of batch 0 into buf0
    for (int it = tid; it < nitems; it += BTHREADS) {
        const int r = it >> 5, v = it & 31;
        const float4 a = *reinterpret_cast<const float4*>(featB + (size_t)r * ND + v * 4);
        uint2 wv; wv.x = cvt_pk_bf16(a.x, a.y); wv.y = cvt_pk_bf16(a.z, a.w);
        *reinterpret_cast<uint2*>(
            &sm.buf[0][r * 128 + (((v >> 1) ^ (r & 7)) << 3) + (v & 1) * 4]) = wv;
    }
    __syncthreads();

    const int tailN = nitems - 3 * BTHREADS;     // 224 (pass0) / 256 (pass1)

    for (int i = 0; i < NBATCH; ++i) {
        const float* fi = featB + (size_t)i * nrows * ND;
        f32x4 acc[4];
#pragma unroll
        for (int rt = 0; rt < 4; ++rt) acc[rt] = f32x4{0.f, 0.f, 0.f, 0.f};

#pragma unroll
        for (int c = 0; c < 4; ++c) {
            const bool haveNext = (c < 3) || (i + 1 < NBATCH);
            const float* fsrc = (c < 3) ? (fi + (c + 1) * 128) : (fi + (size_t)nrows * ND);

            // -- T14: issue stage loads early (held across GEMM)
            float4 L0{}, L1{}, L2{}, L3{};
            if (haveNext) {
                const int i0 = tid, i1 = tid + BTHREADS, i2 = tid + 2 * BTHREADS,
                          i3 = tid + 3 * BTHREADS;
                L0 = *reinterpret_cast<const float4*>(fsrc + (size_t)(i0 >> 5) * ND + (i0 & 31) * 4);
                L1 = *reinterpret_cast<const float4*>(fsrc + (size_t)(i1 >> 5) * ND + (i1 & 31) * 4);
                L2 = *reinterpret_cast<const float4*>(fsrc + (size_t)(i2 >> 5) * ND + (i2 & 31) * 4);
                if (tid < tailN)
                    L3 = *reinterpret_cast<const float4*>(fsrc + (size_t)(i3 >> 5) * ND + (i3 & 31) * 4);
            }

            // -- GEMM current chunk from buf[c&1]: 4 k-steps x 4 r-tiles
#pragma unroll
            for (int lks = 0; lks < 4; ++lks) {
                const int q0 = lks * 4 + g;
#pragma unroll
                for (int rt = 0; rt < 4; ++rt) {
                    const int r = rt * 16 + colg;
                    const short8 f = *reinterpret_cast<const short8*>(
                        &sm.buf[c & 1][r * 128 + ((q0 ^ (r & 7)) << 3)]);
                    acc[rt] = __builtin_amdgcn_mfma_f32_16x16x32_bf16(
                        wreg[c * 4 + lks], f, acc[rt], 0, 0, 0);
                }
            }

            // -- write staged chunk into buf[(c+1)&1]
            if (haveNext) {
                short* dst = sm.buf[(c + 1) & 1];
                const int i0 = tid, i1 = tid + BTHREADS, i2 = tid + 2 * BTHREADS,
                          i3 = tid + 3 * BTHREADS;
#define WR(L, IT) { const int r = (IT) >> 5, v = (IT) & 31; \
                    uint2 wv; wv.x = cvt_pk_bf16((L).x, (L).y); wv.y = cvt_pk_bf16((L).z, (L).w); \
                    *reinterpret_cast<uint2*>(&dst[r * 128 + (((v >> 1) ^ (r & 7)) << 3) + (v & 1) * 4]) = wv; }
                WR(L0, i0) WR(L1, i1) WR(L2, i2)
                if (tid < tailN) WR(L3, i3)
#undef WR
            }
            __syncthreads();
        }

        // ---- epilogue: partial[r] = sum over this wave's 16 n of tanh(S)*wPi
        {
            float sp[4] = {0.f, 0.f, 0.f, 0.f};
#pragma unroll
            for (int rt = 0; rt < 4; ++rt) {
#pragma unroll
                for (int ii = 0; ii < 4; ++ii) {
                    const int n = wid * 16 + g * 4 + ii;
                    const float w = (n < NK) ? wPiRow[n] : 0.f;
                    sp[rt] += fast_tanh(acc[rt][ii]) * w;
                }
            }
#pragma unroll
            for (int rt = 0; rt < 4; ++rt) {
                sp[rt] += __shfl_xor(sp[rt], 16);
                sp[rt] += __shfl_xor(sp[rt], 32);
            }
            if (g == 0) {
#pragma unroll
                for (int rt = 0; rt < 4; ++rt)
                    sm.part[wid][rt * 16 + colg] = sp[rt];
            }
        }
        __syncthreads();

        if (tid < 64) {   // softmax over rows
            float v = (tid < nrows) ? bvec[tid] : 0.f;
#pragma unroll
            for (int w = 0; w < NT; ++w) v += sm.part[w][tid];
            v = (tid < nrows) ? v : -3.0e38f;
            float mx = v;
#pragma unroll
            for (int off = 32; off; off >>= 1) mx = fmaxf(mx, __shfl_xor(mx, off));
            const float e = (tid < nrows) ? __expf(v - mx) : 0.f;
            float su = e;
#pragma unroll
            for (int off = 32; off; off >>= 1) su += __shfl_xor(su, off);
            sm.P[tid] = e / su;
        }
        __syncthreads();

        // ---- weighted sum (global f32, L2-hot) + atomic combine
        {
            const size_t bout = (size_t)(grp * NBATCH + i) * ND;
            for (int cc = tid; cc < ND; cc += BTHREADS) {
                float v = 0.f;
                const float* fp = fi + cc;
                for (int r = 0; r < nrows; ++r) v += sm.P[r] * fp[(size_t)r * ND];
                atomicAdd(&out[bout + cc], v);
            }
        }
    }
}

extern "C" void kernel_launch(void* const* d_in, const int* in_sizes, int n_in,
                              void* d_out, int out_size, void* d_ws, size_t ws_size,
                              hipStream_t stream) {
    const float* ifeat = (const float*)d_in[0];
    const float* tfeat = (const float*)d_in[1];
    const float* wVi0  = (const float*)d_in[2];
    const float* wPi0  = (const float*)d_in[4];
    const float* bPi0  = (const float*)d_in[5];
    const float* wVt1  = (const float*)d_in[7];
    const float* wPi1  = (const float*)d_in[8];
    const float* bPi1  = (const float*)d_in[9];
    float* outp = (float*)d_out;
    unsigned short* wsW = (unsigned short*)d_ws;   // 2*114688 = 229376 B

    hipMemsetAsync(outp, 0, (size_t)NB * ND * sizeof(float), stream);
    hipLaunchKernelGGL(preswz_kernel, dim3(NT * KSTEPS, 2), dim3(64), 0, stream,
                       wVi0, wVt1, wsW);
    hipLaunchKernelGGL(coattn_main, dim3(2 * NGRP), dim3(BTHREADS), 0, stream,
                       ifeat, tfeat, wPi0, bPi0, wPi1, bPi1, wsW, outp);
}

// Round 9
// 306.394 us; speedup vs baseline: 2.6987x; 2.6987x over previous
//
#include <hip/hip_runtime.h>
#include <math.h>

#define NB 4096
#define NR 49
#define NS 50
#define ND 512
#define NK 100
#define NT 7            // n-tiles of 16 cols (112 >= 100); wave w owns tile w
#define KSTEPS 16       // 512 / 32 (global k-steps)
#define CHUNK_KS 8      // k-steps per LDS chunk (256 cols)
#define FRAGS (NT * KSTEPS * 64 * 8)   // 57344 ushorts (114688 B) per weight matrix

typedef __attribute__((ext_vector_type(8))) short short8;
typedef __attribute__((ext_vector_type(4))) float f32x4;

__device__ __forceinline__ unsigned short f32_bf16(float f) {
    union { float f; unsigned u; } x; x.f = f;
    return (unsigned short)((x.u + 0x7fffu + ((x.u >> 16) & 1u)) >> 16);  // RNE
}
__device__ __forceinline__ unsigned cvt_pk_bf16(float lo, float hi) {
    unsigned r;
    asm("v_cvt_pk_bf16_f32 %0, %1, %2" : "=v"(r) : "v"(lo), "v"(hi));
    return r;
}
__device__ __forceinline__ float fast_tanh(float x) {
    const float ax = fabsf(x);
    const float e = __expf(2.f * ax);            // inf for large ax -> r = 1
    const float r = 1.f - 2.f / (e + 1.f);
    return copysignf(r, x);
}

// ---------------------------------------------------------------------------
// Pre-pass: 2 weight matrices [512][100] f32 -> bf16 MFMA B-fragments.
// (Only w_Vi_0 / w_Vt_1 needed: broadcast conditioning branches cancel in
//  softmax; the two attention passes are fully independent.)
// frag(t, gk): lane l holds W[k = gk*32 + (l>>4)*8 + j][col = t*16 + (l&15)].
// ---------------------------------------------------------------------------
__global__ void preswz_kernel(const float* __restrict__ w0, const float* __restrict__ w1,
                              unsigned short* __restrict__ ws)
{
    const int l  = threadIdx.x;          // 64
    const int gk = blockIdx.x & 15;
    const int t  = blockIdx.x >> 4;      // 0..6
    const int m  = blockIdx.y;           // 0..1
    const float* W = m ? w1 : w0;
    const int col = t * 16 + (l & 15);
    const int k0  = gk * 32 + (l >> 4) * 8;
    unsigned short* o = ws + (size_t)m * FRAGS + ((size_t)(t * 16 + gk) * 64 + l) * 8;
#pragma unroll
    for (int j = 0; j < 8; ++j) {
        float v = (col < NK) ? W[(size_t)(k0 + j) * NK + col] : 0.f;
        o[j] = f32_bf16(v);
    }
}

// ---------------------------------------------------------------------------
// Main kernel: one block per (batch, pass), 512 threads (8 waves).
// Wave w < 7 owns n-tile w and computes all 4 row-tiles against it, so each
// weight fragment is read exactly once per block (112 KB vs R6's 512 KB).
// Each block: stage features -> GEMM scores -> softmax -> weighted sum ->
// atomicAdd into out (pre-zeroed; 2 commutative f32 adds = deterministic).
// ---------------------------------------------------------------------------
struct SM {
    short buf[NS * 256];     // 25600 B: bf16 feature K-chunk [50 rows][256 cols]
    float part[NT][64];      // per-wave (n-tile) row partials
    float P[64];
};

__global__ __launch_bounds__(512, 4) void coattn_main(
    const float* __restrict__ ifeat, const float* __restrict__ tfeat,
    const float* __restrict__ wPi0, const float* __restrict__ bPi0,
    const float* __restrict__ wPi1, const float* __restrict__ bPi1,
    const unsigned short* __restrict__ wsW, float* __restrict__ out)
{
    __shared__ SM sm;
    const int pass = blockIdx.x & 1;
    const int b    = blockIdx.x >> 1;
    const int tid  = threadIdx.x;

    const float* feat = pass ? (tfeat + (size_t)b * NS * ND) : (ifeat + (size_t)b * NR * ND);
    const int nrows  = pass ? NS : NR;
    const int nclamp = nrows - 1;
    const unsigned short* wsR = wsW + (size_t)pass * FRAGS;
    const float* wPiRow = pass ? (wPi1 + NK) : wPi0;
    const float* bvec   = pass ? bPi1 : bPi0;

    const int lane = tid & 63, wid = tid >> 6;   // wid 0..6 = n-tile; wid 7 stages only
    const int colg = lane & 15, g = lane >> 4;

    const f32x4 zero4 = {0.f, 0.f, 0.f, 0.f};
    f32x4 acc[4] = {zero4, zero4, zero4, zero4};

    // precompute clamped row + swizzle per row-tile
    int arow_[4], rswz_[4];
#pragma unroll
    for (int rt = 0; rt < 4; ++rt) {
        const int r0 = rt * 16 + colg;
        arow_[rt] = (r0 < nclamp) ? r0 : nclamp;
        rswz_[rt] = arow_[rt] & 7;
    }

    const int nitems = nrows * 32;

    for (int chunk = 0; chunk < 2; ++chunk) {
        __syncthreads();   // buf free (prior chunk's GEMM done)
        // ---- stage chunk: global f32 -> bf16 LDS, 16B-chunk XOR swizzle
        for (int it = tid; it < nitems; it += 512) {
            const int r = it >> 5, c = it & 31;
            const float* p = feat + (r << 9) + (chunk << 8) + (c << 3);
            const float4 a  = *reinterpret_cast<const float4*>(p);
            const float4 b4 = *reinterpret_cast<const float4*>(p + 4);
            uint4 v;
            v.x = cvt_pk_bf16(a.x, a.y);   v.y = cvt_pk_bf16(a.z, a.w);
            v.z = cvt_pk_bf16(b4.x, b4.y); v.w = cvt_pk_bf16(b4.z, b4.w);
            *reinterpret_cast<uint4*>(&sm.buf[(r << 8) + ((c ^ (r & 7)) << 3)]) = v;
        }
        __syncthreads();

        // ---- GEMM on this chunk: 8 k-steps x 4 row-tiles, 1 weight frag/kstep
        if (wid < NT) {
            const unsigned short* wl = wsR
                + ((size_t)(wid * KSTEPS + chunk * CHUNK_KS) * 64 + lane) * 8;
#pragma unroll
            for (int ks = 0; ks < CHUNK_KS; ++ks) {
                const short8 w = *reinterpret_cast<const short8*>(wl + ks * 512);
                const int q0 = (ks << 2) + g;
#pragma unroll
                for (int rt = 0; rt < 4; ++rt) {
                    const short8 a = *reinterpret_cast<const short8*>(
                        &sm.buf[(arow_[rt] << 8) + ((q0 ^ rswz_[rt]) << 3)]);
                    acc[rt] = __builtin_amdgcn_mfma_f32_16x16x32_bf16(a, w, acc[rt], 0, 0, 0);
                }
            }
        }
    }

    // ---- epilogue: row partials for this wave's 16 cols
    if (wid < NT) {
        const int col = wid * 16 + colg;
        const float w = (col < NK) ? wPiRow[col] : 0.f;
        float sp[4][4];
#pragma unroll
        for (int rt = 0; rt < 4; ++rt)
#pragma unroll
            for (int i = 0; i < 4; ++i)
                sp[rt][i] = fast_tanh(acc[rt][i]) * w;
        // reduce over the 16 col-lanes (bits 0..3 of lane)
#pragma unroll
        for (int off = 1; off < 16; off <<= 1)
#pragma unroll
            for (int rt = 0; rt < 4; ++rt)
#pragma unroll
                for (int i = 0; i < 4; ++i)
                    sp[rt][i] += __shfl_xor(sp[rt][i], off);
        if (colg == 0) {
#pragma unroll
            for (int rt = 0; rt < 4; ++rt)
#pragma unroll
                for (int i = 0; i < 4; ++i)
                    sm.part[wid][rt * 16 + g * 4 + i] = sp[rt][i];
        }
    }
    __syncthreads();

    if (tid < 64) {   // softmax over rows
        float v = (tid < nrows) ? bvec[tid] : 0.f;
#pragma unroll
        for (int w = 0; w < NT; ++w) v += sm.part[w][tid];
        v = (tid < nrows) ? v : -3.0e38f;
        float mx = v;
#pragma unroll
        for (int off = 32; off; off >>= 1) mx = fmaxf(mx, __shfl_xor(mx, off));
        const float e = (tid < nrows) ? __expf(v - mx) : 0.f;
        float su = e;
#pragma unroll
        for (int off = 32; off; off >>= 1) su += __shfl_xor(su, off);
        sm.P[tid] = e / su;
    }
    __syncthreads();

    // ---- weighted sum: V[tid] = sum_r P[r] * feat[r, tid]  (global f32, L2/L3-hot)
    {
        float v = 0.f;
        const float* fp = feat + tid;
        for (int r = 0; r < nrows; ++r) v += sm.P[r] * fp[r << 9];
        atomicAdd(&out[(size_t)b * ND + tid], v);
    }
}

extern "C" void kernel_launch(void* const* d_in, const int* in_sizes, int n_in,
                              void* d_out, int out_size, void* d_ws, size_t ws_size,
                              hipStream_t stream) {
    const float* ifeat = (const float*)d_in[0];
    const float* tfeat = (const float*)d_in[1];
    const float* wVi0  = (const float*)d_in[2];
    const float* wPi0  = (const float*)d_in[4];
    const float* bPi0  = (const float*)d_in[5];
    const float* wVt1  = (const float*)d_in[7];
    const float* wPi1  = (const float*)d_in[8];
    const float* bPi1  = (const float*)d_in[9];
    float* outp = (float*)d_out;
    unsigned short* wsW = (unsigned short*)d_ws;   // 2*114688 = 229376 B

    hipMemsetAsync(outp, 0, (size_t)NB * ND * sizeof(float), stream);
    hipLaunchKernelGGL(preswz_kernel, dim3(NT * KSTEPS, 2), dim3(64), 0, stream,
                       wVi0, wVt1, wsW);
    hipLaunchKernelGGL(coattn_main, dim3(2 * NB), dim3(512), 0, stream,
                       ifeat, tfeat, wPi0, bPi0, wPi1, bPi1, wsW, outp);
}